// Round 3
// baseline (135.318 us; speedup 1.0000x reference)
//
#include <hip/hip_runtime.h>
#include <hip/hip_bf16.h>

#define IN_DIMS  8192
#define OUT_DIMS 8192
#define NLAB     63
#define KS       16                   // split-K factor
#define KCH      (IN_DIMS / KS)       // 512 K per workgroup

typedef short  s16x8 __attribute__((ext_vector_type(8)));
typedef float  f32x4 __attribute__((ext_vector_type(4)));

// ---- bf16 RNE pack helpers ----
__device__ __forceinline__ unsigned int rne2(float a, float b) {
    unsigned int ua = __float_as_uint(a), ub = __float_as_uint(b);
    ua += 0x7FFFu + ((ua >> 16) & 1u);
    ub += 0x7FFFu + ((ub >> 16) & 1u);
    return (ua >> 16) | (ub & 0xFFFF0000u);
}

// packed cvt: compiler emits v_cvt_pk_bf16_f32 (RNE), 4 instrs per 8 floats
__device__ __forceinline__ s16x8 cvt8(float4 a, float4 b) {
    union { __hip_bfloat162 h[4]; s16x8 v; } u;
    u.h[0] = __float22bfloat162_rn(make_float2(a.x, a.y));
    u.h[1] = __float22bfloat162_rn(make_float2(a.z, a.w));
    u.h[2] = __float22bfloat162_rn(make_float2(b.x, b.y));
    u.h[3] = __float22bfloat162_rn(make_float2(b.z, b.w));
    return u.v;
}

// ---- kernel 1: Label f32 (63x8192) -> bf16 A (64x8192, row 63 zero) ----
__global__ __launch_bounds__(256) void k_prep(const float* __restrict__ L,
                                              unsigned short* __restrict__ A) {
    int e0 = (blockIdx.x * 256 + threadIdx.x) * 4;
    if (e0 >= 64 * IN_DIMS) return;
    float4 v = make_float4(0.f, 0.f, 0.f, 0.f);
    if (e0 < NLAB * IN_DIMS) v = *(const float4*)(L + e0);
    uint2 o;
    o.x = rne2(v.x, v.y);
    o.y = rne2(v.z, v.w);
    *(uint2*)(A + e0) = o;
}

// ---- kernel 2: split-K MFMA GEMM, depth-2 W pipeline, no LDS/atomics ----
// Xp[kspl] (64x8192 f32) = A(64xKCH) * W(KCH chunk)^T
// Issue order per iter: A-loads first, then next-iter W loads, so the
// compiler's s_waitcnt before MFMA leaves the W prefetch in flight.
__global__ __launch_bounds__(256, 8) void k_gemm(const float* __restrict__ W,
                                                 const unsigned short* __restrict__ A,
                                                 float* __restrict__ Xp) {
    const int nblk = blockIdx.x & 127;   // N tile (64 cols)
    const int kspl = blockIdx.x >> 7;    // K split
    const int wave = threadIdx.x >> 6;
    const int lane = threadIdx.x & 63;
    const int r = lane & 15;             // row-in-16 (A:m, W:n), frag layout
    const int g = lane >> 4;             // k-group (8 elems each)

    const int n0    = nblk * 64 + wave * 16;
    const int kbase = kspl * KCH + g * 8;

    const float*          wp  = W + (long)(n0 + r) * IN_DIMS + kbase;
    const unsigned short* ap0 = A + (long)r * IN_DIMS + kbase;
    const unsigned short* ap1 = ap0 + 16L * IN_DIMS;
    const unsigned short* ap2 = ap0 + 32L * IN_DIMS;
    const unsigned short* ap3 = ap0 + 48L * IN_DIMS;

    f32x4 acc0 = {0.f,0.f,0.f,0.f}, acc1 = {0.f,0.f,0.f,0.f};
    f32x4 acc2 = {0.f,0.f,0.f,0.f}, acc3 = {0.f,0.f,0.f,0.f};

    // pipeline prologue: current W tile in registers
    float4 w0 = *(const float4*)(wp);
    float4 w1 = *(const float4*)(wp + 4);

    #pragma unroll 4
    for (int kk = 0; kk < KCH; kk += 32) {
        // current-iter A loads (issued before the W prefetch!)
        s16x8 a0 = *(const s16x8*)(ap0 + kk);
        s16x8 a1 = *(const s16x8*)(ap1 + kk);
        s16x8 a2 = *(const s16x8*)(ap2 + kk);
        s16x8 a3 = *(const s16x8*)(ap3 + kk);
        // next-iter W prefetch (clamped in-bounds, branchless, wave-uniform)
        int knext = (kk + 32 < KCH) ? (kk + 32) : 0;
        float4 nw0 = *(const float4*)(wp + knext);
        float4 nw1 = *(const float4*)(wp + knext + 4);

        s16x8 bw = cvt8(w0, w1);             // B-frag: B[k][n], n = n0+r
        acc0 = __builtin_amdgcn_mfma_f32_16x16x32_bf16(a0, bw, acc0, 0, 0, 0);
        acc1 = __builtin_amdgcn_mfma_f32_16x16x32_bf16(a1, bw, acc1, 0, 0, 0);
        acc2 = __builtin_amdgcn_mfma_f32_16x16x32_bf16(a2, bw, acc2, 0, 0, 0);
        acc3 = __builtin_amdgcn_mfma_f32_16x16x32_bf16(a3, bw, acc3, 0, 0, 0);

        w0 = nw0; w1 = nw1;                  // rotate pipeline
    }

    // D layout: lane holds D[m = t*16 + g*4 + q][n = n0 + r]; plain stores
    float* xo = Xp + (long)kspl * 64 * OUT_DIMS + n0 + r;
    #pragma unroll
    for (int q = 0; q < 4; ++q) {
        int m = g * 4 + q;
        xo[(long)(m     ) * OUT_DIMS] = acc0[q];
        xo[(long)(m + 16) * OUT_DIMS] = acc1[q];
        xo[(long)(m + 32) * OUT_DIMS] = acc2[q];
        xo[(long)(m + 48) * OUT_DIMS] = acc3[q];
    }
}

// ---- kernel 3: out(63x8192) = S(63x63) @ relu(sum_k Xp + b).view(8192,63)^T ----
__global__ __launch_bounds__(256) void k_out(const float* __restrict__ Xp,
                                             const float* __restrict__ S,
                                             const float* __restrict__ b,
                                             float* __restrict__ out) {
    __shared__ float sS[NLAB * NLAB];    // 63x63
    __shared__ float sml[64 * NLAB];     // 64 output-columns worth of ML rows
    const int k0 = blockIdx.x * 64;

    for (int p = threadIdx.x; p < NLAB * NLAB; p += 256) sS[p] = S[p];
    for (int p = threadIdx.x; p < 64 * NLAB; p += 256) {
        int gi = k0 * NLAB + p;          // flat index into X (row-major 63x8192)
        float v = 0.f;
        #pragma unroll
        for (int s = 0; s < KS; ++s)     // reduce split-K partials
            v += Xp[(long)s * 64 * OUT_DIMS + gi];
        v += b[gi & (OUT_DIMS - 1)];
        sml[p] = v > 0.f ? v : 0.f;
    }
    __syncthreads();

    for (int p = threadIdx.x; p < NLAB * 64; p += 256) {
        int i  = p >> 6;                 // output row (wave-uniform)
        int kk = p & 63;                 // output col within tile (= lane)
        const float* srow = &sS[i * NLAB];
        const float* mrow = &sml[kk * NLAB];
        float sum = 0.f;
        #pragma unroll
        for (int j = 0; j < NLAB; ++j) sum += srow[j] * mrow[j];
        out[(long)i * OUT_DIMS + k0 + kk] = sum;
    }
}

extern "C" void kernel_launch(void* const* d_in, const int* in_sizes, int n_in,
                              void* d_out, int out_size, void* d_ws, size_t ws_size,
                              hipStream_t stream) {
    const float* Label = (const float*)d_in[0];   // 63x8192
    const float* S     = (const float*)d_in[1];   // 63x63
    const float* W     = (const float*)d_in[2];   // 8192x8192
    const float* b     = (const float*)d_in[3];   // 8192
    float* out = (float*)d_out;

    unsigned short* A  = (unsigned short*)d_ws;                      // 1 MB bf16 A
    float*          Xp = (float*)((char*)d_ws + 64 * IN_DIMS * 2);   // KS x 2 MB partials

    k_prep<<<dim3((64 * IN_DIMS / 4 + 255) / 256), dim3(256), 0, stream>>>(Label, A);
    k_gemm<<<dim3(128 * KS), dim3(256), 0, stream>>>(W, A, Xp);
    k_out <<<dim3(OUT_DIMS / 64), dim3(256), 0, stream>>>(Xp, S, b, out);
}

// Round 4
// 92.004 us; speedup vs baseline: 1.4708x; 1.4708x over previous
//
#include <hip/hip_runtime.h>
#include <hip/hip_bf16.h>

#define IN_DIMS  8192
#define OUT_DIMS 8192
#define NLAB     63
#define KS       8                    // split-K factor
#define KCH      (IN_DIMS / KS)       // 1024 K per workgroup
#define BK       64                   // K per LDS tile
#define NT       (KCH / BK)           // 16 tiles
#define BN       64                   // W rows (N) per workgroup

// LDS layout per buffer: W tile 64x64 f32 (16KB, 256B rows) + A tile 64x64 bf16 (8KB, 128B rows)
#define BUFB     24576                // bytes per buffer
#define AOFF     16384                // A offset within buffer

typedef short  s16x8 __attribute__((ext_vector_type(8)));
typedef float  f32x4 __attribute__((ext_vector_type(4)));
typedef unsigned int u32;

__device__ __forceinline__ void gload16(const void* g, void* l) {
    __builtin_amdgcn_global_load_lds(
        (const __attribute__((address_space(1))) u32*)g,
        (__attribute__((address_space(3))) u32*)l, 16, 0, 0);
}

// ---- bf16 RNE pack helpers ----
__device__ __forceinline__ unsigned int rne2(float a, float b) {
    unsigned int ua = __float_as_uint(a), ub = __float_as_uint(b);
    ua += 0x7FFFu + ((ua >> 16) & 1u);
    ub += 0x7FFFu + ((ub >> 16) & 1u);
    return (ua >> 16) | (ub & 0xFFFF0000u);
}

// packed cvt: v_cvt_pk_bf16_f32 (RNE), 4 instrs per 8 floats
__device__ __forceinline__ s16x8 cvt8(float4 a, float4 b) {
    union { __hip_bfloat162 h[4]; s16x8 v; } u;
    u.h[0] = __float22bfloat162_rn(make_float2(a.x, a.y));
    u.h[1] = __float22bfloat162_rn(make_float2(a.z, a.w));
    u.h[2] = __float22bfloat162_rn(make_float2(b.x, b.y));
    u.h[3] = __float22bfloat162_rn(make_float2(b.z, b.w));
    return u.v;
}

// ---- kernel 1: Label f32 (63x8192) -> bf16 A (64x8192, row 63 zero) ----
__global__ __launch_bounds__(256) void k_prep(const float* __restrict__ L,
                                              unsigned short* __restrict__ A) {
    int e0 = (blockIdx.x * 256 + threadIdx.x) * 4;
    if (e0 >= 64 * IN_DIMS) return;
    float4 v = make_float4(0.f, 0.f, 0.f, 0.f);
    if (e0 < NLAB * IN_DIMS) v = *(const float4*)(L + e0);
    uint2 o;
    o.x = rne2(v.x, v.y);
    o.y = rne2(v.z, v.w);
    *(uint2*)(A + e0) = o;
}

// ---- kernel 2: LDS-staged split-K MFMA GEMM, counted-vmcnt 2-phase pipeline ----
// LDS[row][slot16B] holds global[row][slot ^ (row&7)] (pre-swizzled source, rule #21),
// so ds_read_b128 fragment reads are bank-conflict-free.
__global__ __launch_bounds__(256, 3) void k_gemm(const float* __restrict__ W,
                                                 const unsigned short* __restrict__ A,
                                                 float* __restrict__ Xp) {
    extern __shared__ char lds[];
    const int nblk = blockIdx.x & 127;   // N tile (64 cols of X = rows of W)
    const int kspl = blockIdx.x >> 7;    // K split
    const int w    = threadIdx.x >> 6;   // wave 0..3
    const int l    = threadIdx.x & 63;
    const int r    = l & 15;             // frag row-in-16
    const int g    = l >> 4;             // frag k-group

    const int n0 = nblk * BN;

    f32x4 acc0 = {0,0,0,0}, acc1 = {0,0,0,0}, acc2 = {0,0,0,0}, acc3 = {0,0,0,0};

    // --- staging lambda: 6 global_load_lds per wave per tile (4 W + 2 A) ---
    auto stage = [&](int tt, int b) {
        const int k0 = kspl * KCH + tt * BK;          // element offset (f32 for W, bf16 for A)
        char* base = lds + b * BUFB;
        #pragma unroll
        for (int i = 0; i < 4; ++i) {                 // W: rows w*16 .. w*16+15
            int j    = w * 4 + i;
            int row  = j * 4 + (l >> 4);
            int slot = (l & 15) ^ (row & 7);
            gload16(W + (long)(n0 + row) * IN_DIMS + k0 + slot * 4,
                    base + j * 1024 + l * 16);
        }
        #pragma unroll
        for (int i = 0; i < 2; ++i) {                 // A: rows w*16 .. (8 per instr)
            int j2   = w * 2 + i;
            int row  = j2 * 8 + (l >> 3);
            int slot = (l & 7) ^ (l >> 3);            // row&7 == l>>3
            gload16(A + (long)row * IN_DIMS + k0 + slot * 8,
                    base + AOFF + j2 * 1024 + l * 16);
        }
    };

    stage(0, 0);                                      // prologue

    for (int t = 0; t < NT; ++t) {
        if (t + 1 < NT) {
            stage(t + 1, (t + 1) & 1);                // keep next tile in flight
            asm volatile("s_waitcnt vmcnt(6)" ::: "memory");   // tile t done, t+1 in flight
        } else {
            asm volatile("s_waitcnt vmcnt(0)" ::: "memory");
        }
        __builtin_amdgcn_s_barrier();
        asm volatile("" ::: "memory");

        const char* base = lds + (t & 1) * BUFB;
        const float* ldsW = (const float*)base;
        const unsigned short* ldsA = (const unsigned short*)(base + AOFF);
        #pragma unroll
        for (int kk = 0; kk < 2; ++kk) {
            int rowb = w * 16 + r;
            int s0 = (kk * 8 + g * 2    ) ^ (r & 7);
            int s1 = (kk * 8 + g * 2 + 1) ^ (r & 7);
            float4 w0 = *(const float4*)(ldsW + rowb * 64 + s0 * 4);
            float4 w1 = *(const float4*)(ldsW + rowb * 64 + s1 * 4);
            s16x8 bw = cvt8(w0, w1);
            int sa = (kk * 4 + g) ^ (r & 7);
            s16x8 a0 = *(const s16x8*)(ldsA + ( 0 + r) * 64 + sa * 8);
            s16x8 a1 = *(const s16x8*)(ldsA + (16 + r) * 64 + sa * 8);
            s16x8 a2 = *(const s16x8*)(ldsA + (32 + r) * 64 + sa * 8);
            s16x8 a3 = *(const s16x8*)(ldsA + (48 + r) * 64 + sa * 8);
            acc0 = __builtin_amdgcn_mfma_f32_16x16x32_bf16(a0, bw, acc0, 0, 0, 0);
            acc1 = __builtin_amdgcn_mfma_f32_16x16x32_bf16(a1, bw, acc1, 0, 0, 0);
            acc2 = __builtin_amdgcn_mfma_f32_16x16x32_bf16(a2, bw, acc2, 0, 0, 0);
            acc3 = __builtin_amdgcn_mfma_f32_16x16x32_bf16(a3, bw, acc3, 0, 0, 0);
        }
        asm volatile("" ::: "memory");
        __builtin_amdgcn_s_barrier();                 // protect buffer before re-stage
    }

    // D layout: lane holds D[m = t*16 + g*4 + q][n = n0 + w*16 + r]
    float* xo = Xp + (long)kspl * BN * OUT_DIMS + n0 + w * 16 + r;
    #pragma unroll
    for (int q = 0; q < 4; ++q) {
        int m = g * 4 + q;
        xo[(long)(m     ) * OUT_DIMS] = acc0[q];
        xo[(long)(m + 16) * OUT_DIMS] = acc1[q];
        xo[(long)(m + 32) * OUT_DIMS] = acc2[q];
        xo[(long)(m + 48) * OUT_DIMS] = acc3[q];
    }
}

// ---- kernel 3: out(63x8192) = S(63x63) @ relu(sum_k Xp + b).view(8192,63)^T ----
__global__ __launch_bounds__(256) void k_out(const float* __restrict__ Xp,
                                             const float* __restrict__ S,
                                             const float* __restrict__ b,
                                             float* __restrict__ out) {
    __shared__ float sS[NLAB * NLAB];
    __shared__ float sml[64 * NLAB];
    const int k0 = blockIdx.x * 64;

    for (int p = threadIdx.x; p < NLAB * NLAB; p += 256) sS[p] = S[p];
    for (int p = threadIdx.x; p < 64 * NLAB; p += 256) {
        int gi = k0 * NLAB + p;
        float v = 0.f;
        #pragma unroll
        for (int s = 0; s < KS; ++s)
            v += Xp[(long)s * 64 * OUT_DIMS + gi];
        v += b[gi & (OUT_DIMS - 1)];
        sml[p] = v > 0.f ? v : 0.f;
    }
    __syncthreads();

    for (int p = threadIdx.x; p < NLAB * 64; p += 256) {
        int i  = p >> 6;
        int kk = p & 63;
        const float* srow = &sS[i * NLAB];
        const float* mrow = &sml[kk * NLAB];
        float sum = 0.f;
        #pragma unroll
        for (int j = 0; j < NLAB; ++j) sum += srow[j] * mrow[j];
        out[(long)i * OUT_DIMS + k0 + kk] = sum;
    }
}

extern "C" void kernel_launch(void* const* d_in, const int* in_sizes, int n_in,
                              void* d_out, int out_size, void* d_ws, size_t ws_size,
                              hipStream_t stream) {
    const float* Label = (const float*)d_in[0];   // 63x8192
    const float* S     = (const float*)d_in[1];   // 63x63
    const float* W     = (const float*)d_in[2];   // 8192x8192
    const float* b     = (const float*)d_in[3];   // 8192
    float* out = (float*)d_out;

    unsigned short* A  = (unsigned short*)d_ws;                      // 1 MB bf16 A
    float*          Xp = (float*)((char*)d_ws + 64 * IN_DIMS * 2);   // KS x 2 MB partials

    k_prep<<<dim3((64 * IN_DIMS / 4 + 255) / 256), dim3(256), 0, stream>>>(Label, A);
    k_gemm<<<dim3(128 * KS), dim3(256), 2 * BUFB, stream>>>(W, A, Xp);
    k_out <<<dim3(OUT_DIMS / 64), dim3(256), 0, stream>>>(Xp, S, b, out);
}